// Round 9
// baseline (94.911 us; speedup 1.0000x reference)
//
#include <hip/hip_runtime.h>

#define PHH 7
#define PWW 7
static constexpr float SPATIAL_SCALE = 0.0625f;

// Antiderivative of hat function phi(t) = max(0, 1-|t|), saturating to [0,1].
__device__ __forceinline__ float hat_int(float t) {
    t = fminf(fmaxf(t, -1.0f), 1.0f);
    float a = t + 1.0f, b = 1.0f - t;
    return (t <= 0.0f) ? 0.5f * a * a : 1.0f - 0.5f * b * b;
}

// Exact 1D integral of the hat basis at grid node g over [lo, hi].
__device__ __forceinline__ float bin_w(float lo, float hi, float g) {
    return hat_int(hi - g) - hat_int(lo - g);
}

__device__ __forceinline__ unsigned short f32_to_bf16_rne(float x) {
    unsigned int u = __float_as_uint(x);
    unsigned int r = 0x7FFFu + ((u >> 16) & 1u);
    return (unsigned short)((u + r) >> 16);
}

__device__ __forceinline__ float bf_lo(unsigned int v) {
    return __uint_as_float(v << 16);
}
__device__ __forceinline__ float bf_hi(unsigned int v) {
    return __uint_as_float(v & 0xFFFF0000u);
}

// NCHW f32 -> NHWC bf16 transpose, 64x64 tiles. Reads 4B/lane coalesced,
// writes packed uint (2 bf16 channels) = 4B/lane coalesced (v1 wrote 2B/lane
// ushort -> only 4.7 TB/s; this targets ~6 TB/s on the 71 MB of traffic).
// Also resets the pool kernel's work-queue counter (stream-ordered).
__global__ __launch_bounds__(256) void transpose_nchw_nhwc_bf16_v2(
    const float* __restrict__ src, unsigned short* __restrict__ dst,
    int C, int HW, int* __restrict__ counter)
{
    if (blockIdx.x == 0 && blockIdx.y == 0 && blockIdx.z == 0 && threadIdx.x == 0)
        *counter = 0;

    __shared__ unsigned short tile[64][66];  // +2 pad: write-phase reads ~2-way max
    const int n = blockIdx.z;
    const int hw0 = blockIdx.x * 64;
    const int c0 = blockIdx.y * 64;
    const float* s = src + (size_t)n * C * HW;
    unsigned short* d = dst + (size_t)n * C * HW;

    const int tx = threadIdx.x & 63;   // hw lane
    const int ty = threadIdx.x >> 6;   // 0..3
    // Read: each wave handles 16 consecutive c rows; 64 lanes = consecutive hw.
    #pragma unroll
    for (int i = 0; i < 16; ++i) {
        const int cl = ty * 16 + i;
        const int c = c0 + cl, hw = hw0 + tx;
        if (c < C && hw < HW)
            tile[cl][tx] = f32_to_bf16_rne(s[(size_t)c * HW + hw]);
    }
    __syncthreads();

    // Write: thread = (c-pair, hw-row); packed uint = channels (2cl, 2cl+1).
    const int cl = threadIdx.x & 31;        // c-pair index 0..31
    const int hb = threadIdx.x >> 5;        // 0..7
    #pragma unroll
    for (int i = 0; i < 8; ++i) {
        const int hwl = hb * 8 + i;
        const int hw = hw0 + hwl;
        const int c = c0 + 2 * cl;
        if (hw < HW && c < C) {
            const unsigned int v = (unsigned int)tile[2 * cl][hwl]
                                 | ((unsigned int)tile[2 * cl + 1][hwl] << 16);
            *(unsigned int*)(d + (size_t)hw * C + c) = v;
        }
    }
}

// Persistent pool kernel with dynamic work queue. Grid = 2048 blocks (8/CU),
// each loops atomicAdd over the R*PHH (roi,p) tasks -> CUs stay saturated,
// no scheduling tail (r8 diagnosis: 2.25 blocks/CU resident, 7 us avg block
// latency at ~1 us work). Per task: 4 waves = (ch-half, col-chunk); wave owns
// 128 channels (lane = uint = 2 bf16 ch) x column chunks of 8 (all nh rows,
// wx applied once per column); ping-pong row prefetch; 2-partial LDS reduce.
__global__ __launch_bounds__(256) void prroi_pool_persist(
    const unsigned short* __restrict__ ft,  // [N, H, W, 256] bf16
    const float* __restrict__ rois,         // [R, 5]
    float* __restrict__ out,                // [R, 256, PHH, PWW]
    int H, int W, int R, int* __restrict__ counter)
{
    const int ntask = R * PHH;
    const int tid = threadIdx.x;
    const int wig = tid >> 6;
    const int lane = tid & 63;
    const int chHalf = wig & 1;
    const int colWave = wig >> 1;
    const int c0 = chHalf * 128 + lane * 2;

    __shared__ float wx8[152 * 8];       // [wi][q] (slot 7 = 0), inv_area folded
    __shared__ float wys[16];
    __shared__ float rbuf[2 * 64 * 15];  // stride 15 (odd): conflict-free
    __shared__ int sh_task;

    while (true) {
        if (tid == 0) sh_task = atomicAdd(counter, 1);
        __syncthreads();                  // broadcast task; protects LDS reuse
        const int task = sh_task;
        if (task >= ntask) break;
        const int r = task / PHH;
        const int p = task % PHH;

        const float* roi = rois + (size_t)r * 5;
        const int b = (int)roi[0];
        const float x1 = roi[1] * SPATIAL_SCALE;
        const float y1 = roi[2] * SPATIAL_SCALE;
        const float x2 = roi[3] * SPATIAL_SCALE;
        const float y2 = roi[4] * SPATIAL_SCALE;
        const float bw = fmaxf(x2 - x1, 0.0f) / (float)PWW;
        const float bh = fmaxf(y2 - y1, 0.0f) / (float)PHH;
        const float area = bw * bh;
        const float inv_area = (area > 0.0f) ? 1.0f / fmaxf(area, 1e-12f) : 0.0f;

        const float ylo = y1 + (float)p * bh;
        const float yhi = ylo + bh;
        const int h0 = max(0, (int)ceilf(ylo - 1.0f));
        const int h1 = min(H - 1, (int)floorf(yhi + 1.0f));
        const int w0 = max(0, (int)ceilf(x1 - 1.0f));
        const int w1 = min(W - 1, (int)floorf(x2 + 1.0f));
        const int nh = min(h1 - h0 + 1, 16);
        const int ww = w1 - w0 + 1;
        const int wwpad = (ww + 7) & ~7;

        for (int i = tid; i < wwpad; i += 256) {
            const float g = (float)(w0 + i);
            #pragma unroll
            for (int q = 0; q < PWW; ++q) {
                const float lo = x1 + (float)q * bw;
                wx8[i * 8 + q] = (i < ww) ? bin_w(lo, lo + bw, g) * inv_area : 0.0f;
            }
            wx8[i * 8 + 7] = 0.0f;
        }
        for (int i = tid; i < nh; i += 256)
            wys[i] = bin_w(ylo, yhi, (float)(h0 + i));
        __syncthreads();

        float acc[PWW][2];
        #pragma unroll
        for (int q = 0; q < PWW; ++q) { acc[q][0] = 0.0f; acc[q][1] = 0.0f; }

        const size_t rowstride = (size_t)W * 256;
        const unsigned short* base =
            ft + ((size_t)b * H + (size_t)h0) * rowstride + (size_t)w0 * 256 + c0;

        for (int chunk = colWave * 8; chunk < ww; chunk += 16) {
            int off[8];
            #pragma unroll
            for (int j = 0; j < 8; ++j)
                off[j] = (chunk + j < ww) ? (chunk + j) * 256 : 0;

            float u[2][8];
            #pragma unroll
            for (int j = 0; j < 8; ++j) { u[0][j] = 0.0f; u[1][j] = 0.0f; }

            auto load_row = [&](unsigned int (&v)[8], int i) {
                const unsigned short* rp = base + (size_t)i * rowstride;
                #pragma unroll
                for (int j = 0; j < 8; ++j)
                    v[j] = *(const unsigned int*)(rp + off[j]);
            };
            auto fma_row = [&](const unsigned int (&v)[8], float wy) {
                #pragma unroll
                for (int j = 0; j < 8; ++j) {
                    u[0][j] = fmaf(wy, bf_lo(v[j]), u[0][j]);
                    u[1][j] = fmaf(wy, bf_hi(v[j]), u[1][j]);
                }
            };

            unsigned int A[8], B[8];
            load_row(A, 0);
            int i = 0;
            while (true) {
                if (i + 1 < nh) load_row(B, i + 1);
                fma_row(A, wys[i]);
                if (++i >= nh) break;
                if (i + 1 < nh) load_row(A, i + 1);
                fma_row(B, wys[i]);
                if (++i >= nh) break;
            }

            #pragma unroll
            for (int j = 0; j < 8; ++j) {
                const float4 wa = *(const float4*)&wx8[(chunk + j) * 8];
                const float4 wb = *(const float4*)&wx8[(chunk + j) * 8 + 4];
                acc[0][0] = fmaf(wa.x, u[0][j], acc[0][0]);
                acc[0][1] = fmaf(wa.x, u[1][j], acc[0][1]);
                acc[1][0] = fmaf(wa.y, u[0][j], acc[1][0]);
                acc[1][1] = fmaf(wa.y, u[1][j], acc[1][1]);
                acc[2][0] = fmaf(wa.z, u[0][j], acc[2][0]);
                acc[2][1] = fmaf(wa.z, u[1][j], acc[2][1]);
                acc[3][0] = fmaf(wa.w, u[0][j], acc[3][0]);
                acc[3][1] = fmaf(wa.w, u[1][j], acc[3][1]);
                acc[4][0] = fmaf(wb.x, u[0][j], acc[4][0]);
                acc[4][1] = fmaf(wb.x, u[1][j], acc[4][1]);
                acc[5][0] = fmaf(wb.y, u[0][j], acc[5][0]);
                acc[5][1] = fmaf(wb.y, u[1][j], acc[5][1]);
                acc[6][0] = fmaf(wb.z, u[0][j], acc[6][0]);
                acc[6][1] = fmaf(wb.z, u[1][j], acc[6][1]);
            }
        }

        float* pbuf = rbuf + chHalf * (64 * 15) + lane * 15;
        if (colWave == 1) {
            #pragma unroll
            for (int q = 0; q < PWW; ++q) {
                pbuf[q * 2 + 0] = acc[q][0];
                pbuf[q * 2 + 1] = acc[q][1];
            }
        }
        __syncthreads();
        if (colWave == 0) {
            float* o = out + ((size_t)r * 256 + c0) * (PHH * PWW) + p * PWW;
            #pragma unroll
            for (int q = 0; q < PWW; ++q) {
                o[q]             = acc[q][0] + pbuf[q * 2 + 0];
                o[PHH * PWW + q] = acc[q][1] + pbuf[q * 2 + 1];
            }
        }
        // Loop: top __syncthreads orders colWave0's rbuf reads before next write.
    }
}

// Fallback (no scratch): one thread per output element, reads NCHW directly.
__global__ __launch_bounds__(256) void prroi_pool_nchw(
    const float* __restrict__ f, const float* __restrict__ rois,
    float* __restrict__ out, int C, int H, int W, int R)
{
    const int idx = blockIdx.x * blockDim.x + threadIdx.x;
    const int total = R * C * PHH * PWW;
    if (idx >= total) return;
    const int q = idx % PWW;
    const int p = (idx / PWW) % PHH;
    const int c = (idx / (PWW * PHH)) % C;
    const int r = idx / (PWW * PHH * C);
    const float* roi = rois + (size_t)r * 5;
    const int b = (int)roi[0];
    const float x1 = roi[1] * SPATIAL_SCALE;
    const float y1 = roi[2] * SPATIAL_SCALE;
    const float x2 = roi[3] * SPATIAL_SCALE;
    const float y2 = roi[4] * SPATIAL_SCALE;
    const float bw = fmaxf(x2 - x1, 0.0f) / (float)PWW;
    const float bh = fmaxf(y2 - y1, 0.0f) / (float)PHH;
    const float area = bw * bh;
    const float inv_area = (area > 0.0f) ? 1.0f / fmaxf(area, 1e-12f) : 0.0f;
    const float xlo = x1 + (float)q * bw, xhi = xlo + bw;
    const float ylo = y1 + (float)p * bh, yhi = ylo + bh;
    const int h0 = max(0, (int)ceilf(ylo - 1.0f));
    const int h1 = min(H - 1, (int)floorf(yhi + 1.0f));
    const int w0 = max(0, (int)ceilf(xlo - 1.0f));
    const int w1 = min(W - 1, (int)floorf(xhi + 1.0f));
    float acc = 0.0f;
    for (int h = h0; h <= h1; ++h) {
        const float wy = bin_w(ylo, yhi, (float)h);
        const float* fr = f + (((size_t)b * C + c) * H + h) * W;
        for (int w = w0; w <= w1; ++w)
            acc = fmaf(wy * bin_w(xlo, xhi, (float)w), fr[w], acc);
    }
    out[idx] = acc * inv_area;
}

extern "C" void kernel_launch(void* const* d_in, const int* in_sizes, int n_in,
                              void* d_out, int out_size, void* d_ws, size_t ws_size,
                              hipStream_t stream)
{
    const float* features = (const float*)d_in[0];
    const float* rois = (const float*)d_in[1];
    float* out = (float*)d_out;

    const int C = 256, H = 152, W = 152;
    const int N = in_sizes[0] / (C * H * W);
    const int R = in_sizes[1] / 5;

    const size_t ft_bytes = (size_t)N * C * H * W * sizeof(unsigned short);
    const size_t ctr_off = 24u * 1024u * 1024u;  // 24 MiB > ft_bytes (23.66 MB)
    if (ws_size >= ctr_off + 64 && ft_bytes <= ctr_off && C == 256) {
        unsigned short* ft = (unsigned short*)d_ws;
        int* counter = (int*)((char*)d_ws + ctr_off);
        const int HW = H * W;
        dim3 tgrid((HW + 63) / 64, (C + 63) / 64, N);
        transpose_nchw_nhwc_bf16_v2<<<tgrid, 256, 0, stream>>>(features, ft, C, HW, counter);
        prroi_pool_persist<<<2048, 256, 0, stream>>>(ft, rois, out, H, W, R, counter);
    } else {
        const int total = R * C * PHH * PWW;
        prroi_pool_nchw<<<(total + 255) / 256, 256, 0, stream>>>(features, rois, out, C, H, W, R);
    }
}